// Round 2
// baseline (511.160 us; speedup 1.0000x reference)
//
#include <hip/hip_runtime.h>
#include <math.h>

#define B   512
#define L   1024
#define K   8
#define NR  512
#define S   20
#define EXT 26
#define SS  (S*S)            // 400
#define ROWF (K*EXT)         // 208 floats per (b,l)
#define BROW (L*ROWF)        // 212992 floats per b
#define HROW (BROW/2)        // 106496 floats per half

__device__ __forceinline__ float softplusf(float x) {
    return fmaxf(x, 0.0f) + log1pf(expf(-fabsf(x)));
}

// ---------------------------------------------------------------------------
// Kernel B: one block per (b,k).
//   1) build Q_k in LDS (symmetrize+softplus, zero diag, freq scale, row-sum
//      diagonal, mue normalization) — identical arithmetic to the reference
//   2) expm(tau_b * Q_k) via scale-by-2^-6, order-16 Taylor, 6 squarings
//   3) stash the 400-float P into BOTH halves of out[b]'s row region
//      (floats [0,3200) of each half) for the two consumer blocks.
// No d_ws usage at all (previous round's 6.5 MB P overflowed d_ws and
// corrupted the harness's pristine input copies).
// ---------------------------------------------------------------------------
__global__ __launch_bounds__(256) void expm_kernel(
    const float* __restrict__ exch,         // K,S,S
    const float* __restrict__ freq,         // S
    const float* __restrict__ tau_kernel,   // NR
    const int*   __restrict__ rate_indices, // B
    float* __restrict__ out)                // stash target
{
    int blk = blockIdx.x;            // b*K + k
    int b = blk / K, kk = blk % K;

    __shared__ float Ash[SS];
    __shared__ float Tbuf[2][SS];
    __shared__ float diag_sh[S];
    __shared__ float mue_sh;
    __shared__ float tau_sh;

    int t = threadIdx.x;

    // --- build Qpre (off-diag, diag slot = 0) into Tbuf[0] ---
    const float* E = exch + kk * SS;
    for (int e = t; e < SS; e += 256) {
        int r = e / S, c = e % S;
        float v = 0.f;
        if (r != c) {
            float x = 0.5f * (E[r*S + c] + E[c*S + r]);
            v = softplusf(x) * freq[c];
        }
        Tbuf[0][e] = v;
    }
    if (t == 0) tau_sh = softplusf(tau_kernel[rate_indices[b]]);
    __syncthreads();

    if (t < S) {
        float d = 0.f;
        #pragma unroll
        for (int j = 0; j < S; ++j) d += Tbuf[0][t*S + j];
        diag_sh[t] = d;
    }
    __syncthreads();

    if (t == 0) {
        float m = 0.f;
        #pragma unroll
        for (int s = 0; s < S; ++s) m += freq[s] * diag_sh[s];
        mue_sh = fmaxf(m, 1e-16f);
    }
    __syncthreads();

    // A = (Q / mue) * (tau * 2^-6); tau*2^-6 is exact, matches ref rounding
    float scale = tau_sh * 0.015625f;
    for (int e = t; e < SS; e += 256) {
        int r = e / S, c = e % S;
        float v = (r == c) ? -diag_sh[r] : Tbuf[0][e];
        Ash[e] = (v / mue_sh) * scale;
    }
    __syncthreads();

    // --- expm (validated in round 1: absmax 3.9e-3 on first launch) ---
    int e0 = t;
    int e1 = t + 256;
    int r0 = e0 / S, c0 = e0 % S;
    bool has1 = (e1 < SS);
    int r1 = has1 ? (e1 / S) : 0, c1 = has1 ? (e1 % S) : 0;

    float acol0[S], acol1[S];
    #pragma unroll
    for (int j = 0; j < S; ++j) {
        acol0[j] = Ash[j*S + c0];
        acol1[j] = has1 ? Ash[j*S + c1] : 0.f;
    }

    float p0 = Ash[e0] + ((r0 == c0) ? 1.f : 0.f);
    float p1 = has1 ? (Ash[e1] + ((r1 == c1) ? 1.f : 0.f)) : 0.f;

    const float* Tcur = Ash;
    int cur = 0;
    for (int i = 2; i <= 16; ++i) {
        float inv = 1.0f / (float)i;
        float t0 = 0.f, t1 = 0.f;
        const float* Trow0 = Tcur + r0 * S;
        const float* Trow1 = Tcur + r1 * S;
        #pragma unroll
        for (int j = 0; j < S; ++j) {
            t0 += Trow0[j] * acol0[j];
            t1 += Trow1[j] * acol1[j];
        }
        t0 *= inv; t1 *= inv;
        Tbuf[cur][e0] = t0;
        if (has1) Tbuf[cur][e1] = t1;
        p0 += t0; p1 += t1;
        __syncthreads();
        Tcur = Tbuf[cur];
        cur ^= 1;
    }

    for (int sq = 0; sq < 6; ++sq) {
        Tbuf[cur][e0] = p0;
        if (has1) Tbuf[cur][e1] = p1;
        __syncthreads();
        const float* Pb = Tbuf[cur];
        float n0 = 0.f, n1 = 0.f;
        #pragma unroll
        for (int j = 0; j < S; ++j) {
            n0 += Pb[r0*S + j] * Pb[j*S + c0];
            n1 += Pb[r1*S + j] * Pb[j*S + c1];
        }
        p0 = n0; p1 = n1;
        cur ^= 1;
        // writes next iter go to the other buffer; safe with one sync/iter
    }

    // --- stash P into both halves of out[b] ---
    size_t obase = (size_t)b * BROW + (size_t)kk * SS;
    out[obase + e0] = p0;
    out[obase + HROW + e0] = p0;
    if (has1) {
        out[obase + e1] = p1;
        out[obase + HROW + e1] = p1;
    }
}

// ---------------------------------------------------------------------------
// Kernel C: one block per (b, half). Loads the stashed P[b] (first 3200
// floats of its own half-region), builds Row[26][208] lookup (symbol -> full
// 208-float output row), then streams out[b][l][:] = Row[inp[l]][:] as
// float4s: 1 ds_read_b128 + 1 global_store_dwordx4 per unit, stores fully
// contiguous per block.
// ---------------------------------------------------------------------------
__global__ __launch_bounds__(512, 8) void write_kernel(
    const int* __restrict__ inputs,  // B,L
    float* __restrict__ out)
{
    __shared__ __align__(16) float Psh[K*SS];       // 3200 floats
    __shared__ __align__(16) float Row[EXT*ROWF];   // 26*208 = 5408 floats
    __shared__ int inp_sh[512];

    int blk = blockIdx.x;
    int b = blk >> 1, h = blk & 1;
    int t = threadIdx.x;

    float* base = out + (size_t)b * BROW + (size_t)h * HROW;

    // load stash (written by expm_kernel) + this half's inputs
    const float4* src4 = (const float4*)base;
    float4* Psh4 = (float4*)Psh;
    for (int u = t; u < (K*SS)/4; u += 512) Psh4[u] = src4[u];
    inp_sh[t] = inputs[b * L + h * (L/2) + t];
    __syncthreads();

    // build lookup rows: symbol<20 -> P rows padded to 26; symbol>=20 -> one-hot
    for (int u = t; u < EXT*ROWF; u += 512) {
        int row = u / ROWF;
        int c   = u - row * ROWF;
        int k   = c / EXT;
        int s   = c - k * EXT;
        float v;
        if (row < S) v = (s < S) ? Psh[k*SS + row*S + s] : 0.f;
        else         v = (s == row) ? 1.f : 0.f;
        Row[u] = v;
    }
    __syncthreads();

    // stream the half-region: 512 l's * 52 float4 = 26624 units, 52/thread
    float4* out4 = (float4*)base;
    for (int u = t; u < (L/2) * (ROWF/4); u += 512) {
        int l = u / (ROWF/4);
        int q = u - l * (ROWF/4);
        const float4* r4 = (const float4*)(Row + inp_sh[l] * ROWF);
        out4[u] = r4[q];
    }
}

// ---------------------------------------------------------------------------
extern "C" void kernel_launch(void* const* d_in, const int* in_sizes, int n_in,
                              void* d_out, int out_size, void* d_ws, size_t ws_size,
                              hipStream_t stream) {
    const int*   inputs  = (const int*)  d_in[0];  // (B,L) int32
    const int*   rate_ix = (const int*)  d_in[1];  // (B,) int32
    const float* tau_k   = (const float*)d_in[2];  // (NR,) f32
    const float* exch    = (const float*)d_in[3];  // (K,S,S) f32
    const float* freq    = (const float*)d_in[4];  // (S,) f32
    float* out = (float*)d_out;

    (void)d_ws; (void)ws_size;  // intentionally unused (round-1 overflow)

    expm_kernel<<<B * K, 256, 0, stream>>>(exch, freq, tau_k, rate_ix, out);
    write_kernel<<<B * 2, 512, 0, stream>>>(inputs, out);
}

// Round 3
// 504.206 us; speedup vs baseline: 1.0138x; 1.0138x over previous
//
#include <hip/hip_runtime.h>
#include <math.h>

#define B   512
#define L   1024
#define K   8
#define NR  512
#define S   20
#define EXT 26
#define SS  (S*S)            // 400
#define PD  24               // padded matrix dim (zero pad, self-consistent)
#define ROWF (K*EXT)         // 208 floats per (b,l)
#define BROW (L*ROWF)        // 212992 floats per b
#define HROW (BROW/2)        // 106496 floats per half

__device__ __forceinline__ float softplusf(float x) {
    return fmaxf(x, 0.0f) + log1pf(expf(-fabsf(x)));
}

// ---------------------------------------------------------------------------
// expm: ONE WAVE per (b,k) matrix. 24x24 zero-padded matrices in LDS,
// 8x8 lane grid, 3x3 register tile per lane. A cached in registers for the
// whole Taylor phase (60 VGPRs); per matmul: 15 ds_read_b128 (row chunks)
// + 180 FMA + 9 LDS writes. Squaring adds 20 b96 column reads. Single-wave
// blocks -> barriers are near-free. Stash P into both halves of out[b].
// ---------------------------------------------------------------------------
__global__ __launch_bounds__(64, 4) void expm_kernel(
    const float* __restrict__ exch,         // K,S,S
    const float* __restrict__ freq,         // S
    const float* __restrict__ tau_kernel,   // NR
    const int*   __restrict__ rate_indices, // B
    float* __restrict__ out)                // stash target
{
    int blk = blockIdx.x;            // b*K + k
    int b = blk / K, kk = blk % K;

    __shared__ __align__(16) float M0[PD*PD];
    __shared__ __align__(16) float M1[PD*PD];
    __shared__ float diag_sh[S];
    __shared__ float mue_sh, tau_sh;

    int t = threadIdx.x;             // 0..63
    int li = t >> 3, lj = t & 7;
    int r0 = 3*li, c0 = 3*lj;        // tile origin (rows/cols up to 23 = pad)

    for (int e = t; e < PD*PD; e += 64) { M0[e] = 0.f; M1[e] = 0.f; }
    if (t == 0) tau_sh = softplusf(tau_kernel[rate_indices[b]]);
    __syncthreads();

    // --- build Qpre (off-diag) into M0, padded layout ---
    const float* E = exch + kk * SS;
    for (int e = t; e < SS; e += 64) {
        int r = e / S, c = e - r*S;
        float v = 0.f;
        if (r != c)
            v = softplusf(0.5f * (E[r*S + c] + E[c*S + r])) * freq[c];
        M0[r*PD + c] = v;
    }
    __syncthreads();
    if (t < S) {
        float d = 0.f;
        #pragma unroll
        for (int j = 0; j < S; ++j) d += M0[t*PD + j];
        diag_sh[t] = d;
    }
    __syncthreads();
    if (t == 0) {
        float m = 0.f;
        #pragma unroll
        for (int s = 0; s < S; ++s) m += freq[s] * diag_sh[s];
        mue_sh = fmaxf(m, 1e-16f);
    }
    __syncthreads();

    // A = (Q/mue) * (tau * 2^-6) in place (M0); pad stays zero
    float scale = tau_sh * 0.015625f;
    for (int e = t; e < SS; e += 64) {
        int r = e / S, c = e - r*S;
        float v = (r == c) ? -diag_sh[r] : M0[r*PD + c];
        M0[r*PD + c] = (v / mue_sh) * scale;
    }
    __syncthreads();

    // --- cache A's 3 columns (c0..c0+2) for all j in registers ---
    float Ac[S][3];
    #pragma unroll
    for (int j = 0; j < S; ++j) {
        #pragma unroll
        for (int d = 0; d < 3; ++d)
            Ac[j][d] = M0[j*PD + c0 + d];   // pad cols read 0
    }

    // P = I + A on my tile (pad diag NOT incremented)
    float P[3][3];
    #pragma unroll
    for (int dr = 0; dr < 3; ++dr)
        #pragma unroll
        for (int dc = 0; dc < 3; ++dc) {
            int r = r0 + dr, c = c0 + dc;
            P[dr][dc] = M0[r*PD + c] + ((r == c && r < S) ? 1.f : 0.f);
        }

    // --- Taylor: T=A; for i=2..16: T = T@A/i; P += T ---
    const float* Tc = M0;
    float* Tn = M1;
    #pragma unroll 1
    for (int i = 2; i <= 16; ++i) {
        float C[3][3] = {{0.f,0.f,0.f},{0.f,0.f,0.f},{0.f,0.f,0.f}};
        #pragma unroll
        for (int jc = 0; jc < 5; ++jc) {
            float4 a0 = *(const float4*)&Tc[(r0+0)*PD + 4*jc];
            float4 a1 = *(const float4*)&Tc[(r0+1)*PD + 4*jc];
            float4 a2 = *(const float4*)&Tc[(r0+2)*PD + 4*jc];
            float t0[4] = {a0.x, a0.y, a0.z, a0.w};
            float t1[4] = {a1.x, a1.y, a1.z, a1.w};
            float t2[4] = {a2.x, a2.y, a2.z, a2.w};
            #pragma unroll
            for (int dj = 0; dj < 4; ++dj) {
                int j = 4*jc + dj;
                #pragma unroll
                for (int dc = 0; dc < 3; ++dc) {
                    C[0][dc] = fmaf(t0[dj], Ac[j][dc], C[0][dc]);
                    C[1][dc] = fmaf(t1[dj], Ac[j][dc], C[1][dc]);
                    C[2][dc] = fmaf(t2[dj], Ac[j][dc], C[2][dc]);
                }
            }
        }
        float inv = 1.0f / (float)i;
        #pragma unroll
        for (int dr = 0; dr < 3; ++dr)
            #pragma unroll
            for (int dc = 0; dc < 3; ++dc) {
                C[dr][dc] *= inv;
                P[dr][dc] += C[dr][dc];
                Tn[(r0+dr)*PD + c0 + dc] = C[dr][dc];
            }
        __syncthreads();
        float* tmp = (float*)Tc; Tc = Tn; Tn = tmp;
    }

    // --- 6 squarings: ping-pong buffers, 1 barrier each ---
    #pragma unroll 1
    for (int sq = 0; sq < 6; ++sq) {
        #pragma unroll
        for (int dr = 0; dr < 3; ++dr)
            #pragma unroll
            for (int dc = 0; dc < 3; ++dc)
                Tn[(r0+dr)*PD + c0 + dc] = P[dr][dc];
        __syncthreads();
        const float* Pb = Tn;
        float C[3][3] = {{0.f,0.f,0.f},{0.f,0.f,0.f},{0.f,0.f,0.f}};
        #pragma unroll
        for (int jc = 0; jc < 5; ++jc) {
            float4 a0 = *(const float4*)&Pb[(r0+0)*PD + 4*jc];
            float4 a1 = *(const float4*)&Pb[(r0+1)*PD + 4*jc];
            float4 a2 = *(const float4*)&Pb[(r0+2)*PD + 4*jc];
            float t0[4] = {a0.x, a0.y, a0.z, a0.w};
            float t1[4] = {a1.x, a1.y, a1.z, a1.w};
            float t2[4] = {a2.x, a2.y, a2.z, a2.w};
            float cb[4][3];
            #pragma unroll
            for (int dj = 0; dj < 4; ++dj)
                #pragma unroll
                for (int dc = 0; dc < 3; ++dc)
                    cb[dj][dc] = Pb[(4*jc + dj)*PD + c0 + dc];
            #pragma unroll
            for (int dj = 0; dj < 4; ++dj)
                #pragma unroll
                for (int dc = 0; dc < 3; ++dc) {
                    C[0][dc] = fmaf(t0[dj], cb[dj][dc], C[0][dc]);
                    C[1][dc] = fmaf(t1[dj], cb[dj][dc], C[1][dc]);
                    C[2][dc] = fmaf(t2[dj], cb[dj][dc], C[2][dc]);
                }
        }
        #pragma unroll
        for (int dr = 0; dr < 3; ++dr)
            #pragma unroll
            for (int dc = 0; dc < 3; ++dc)
                P[dr][dc] = C[dr][dc];
        // next write goes to the other buffer (swap); reads of this buffer
        // are wave-internal and precede next iter's barrier
        float* tmp = (float*)Tc; Tc = Tn; Tn = tmp;
    }

    // --- stash 20x20 P into both halves of out[b] ---
    size_t obase = (size_t)b * BROW + (size_t)kk * SS;
    #pragma unroll
    for (int dr = 0; dr < 3; ++dr) {
        int r = r0 + dr; if (r >= S) continue;
        #pragma unroll
        for (int dc = 0; dc < 3; ++dc) {
            int c = c0 + dc; if (c >= S) continue;
            float v = P[dr][dc];
            out[obase + r*S + c] = v;
            out[obase + HROW + r*S + c] = v;
        }
    }
}

// ---------------------------------------------------------------------------
// write_kernel: unchanged from round 2 (validated). One block per (b, half);
// builds Row[26][208] LUT in LDS, streams out[b][l][:] = Row[inp[l]][:]
// as contiguous float4 stores.
// ---------------------------------------------------------------------------
__global__ __launch_bounds__(512, 8) void write_kernel(
    const int* __restrict__ inputs,  // B,L
    float* __restrict__ out)
{
    __shared__ __align__(16) float Psh[K*SS];       // 3200 floats
    __shared__ __align__(16) float Row[EXT*ROWF];   // 5408 floats
    __shared__ int inp_sh[512];

    int blk = blockIdx.x;
    int b = blk >> 1, h = blk & 1;
    int t = threadIdx.x;

    float* base = out + (size_t)b * BROW + (size_t)h * HROW;

    const float4* src4 = (const float4*)base;
    float4* Psh4 = (float4*)Psh;
    for (int u = t; u < (K*SS)/4; u += 512) Psh4[u] = src4[u];
    inp_sh[t] = inputs[b * L + h * (L/2) + t];
    __syncthreads();

    for (int u = t; u < EXT*ROWF; u += 512) {
        int row = u / ROWF;
        int c   = u - row * ROWF;
        int k   = c / EXT;
        int s   = c - k * EXT;
        float v;
        if (row < S) v = (s < S) ? Psh[k*SS + row*S + s] : 0.f;
        else         v = (s == row) ? 1.f : 0.f;
        Row[u] = v;
    }
    __syncthreads();

    float4* out4 = (float4*)base;
    for (int u = t; u < (L/2) * (ROWF/4); u += 512) {
        int l = u / (ROWF/4);
        int q = u - l * (ROWF/4);
        const float4* r4 = (const float4*)(Row + inp_sh[l] * ROWF);
        out4[u] = r4[q];
    }
}

// ---------------------------------------------------------------------------
extern "C" void kernel_launch(void* const* d_in, const int* in_sizes, int n_in,
                              void* d_out, int out_size, void* d_ws, size_t ws_size,
                              hipStream_t stream) {
    const int*   inputs  = (const int*)  d_in[0];  // (B,L) int32
    const int*   rate_ix = (const int*)  d_in[1];  // (B,) int32
    const float* tau_k   = (const float*)d_in[2];  // (NR,) f32
    const float* exch    = (const float*)d_in[3];  // (K,S,S) f32
    const float* freq    = (const float*)d_in[4];  // (S,) f32
    float* out = (float*)d_out;

    (void)d_ws; (void)ws_size;  // intentionally unused

    expm_kernel<<<B * K, 64, 0, stream>>>(exch, freq, tau_k, rate_ix, out);
    write_kernel<<<B * 2, 512, 0, stream>>>(inputs, out);
}

// Round 4
// 493.899 us; speedup vs baseline: 1.0349x; 1.0209x over previous
//
#include <hip/hip_runtime.h>
#include <math.h>

#define B    512
#define L    1024
#define K    8
#define NR   512
#define S    20
#define EXT  26
#define SS   (S*S)            // 400
#define PD   24               // padded matrix dim (zero pad is matmul-self-consistent)
#define PDSQ (PD*PD)          // 576
#define ROWF (K*EXT)          // 208 floats per (b,l)
#define BROW (L*ROWF)         // 212992 floats per b

__device__ __forceinline__ float softplusf(float x) {
    return fmaxf(x, 0.0f) + log1pf(expf(-fabsf(x)));
}

// ---------------------------------------------------------------------------
// ONE fused kernel. Block = one b (512 blocks, 512 threads = 8 waves).
//   Phase 0: prefetch inputs[b,:] to LDS; fill Row LUT defaults (zeros +
//            one-hot rows for symbols >= 20); zero per-wave matrix buffers.
//   Phase 1: wave w computes P_k=expm(tau_b*Q_k) for k=w in its own LDS
//            patch (8x8 lane grid, 3x3 register tile, A columns cached in
//            registers). Identical arithmetic to round-3 (absmax 1.2e-4).
//            Final P tiles go from registers into Row[r][k*26+c].
//   Phase 2: stream out[b][l][:] = Row[inp[l]][:] as contiguous float4s.
// __launch_bounds__(512, 2): VGPR cap 256 — round 3's (64,4)/(512,8) caps
// (128/64) forced scratch spills in both hot loops; this was the ~3x loss.
// No d_ws, no stash round-trip, no second dispatch.
// ---------------------------------------------------------------------------
__global__ __launch_bounds__(512, 2) void fused_kernel(
    const int*   __restrict__ inputs,        // B,L
    const int*   __restrict__ rate_indices,  // B
    const float* __restrict__ tau_kernel,    // NR
    const float* __restrict__ exch,          // K,S,S
    const float* __restrict__ freq,          // S
    float* __restrict__ out)                 // B,L,208
{
    __shared__ __align__(16) float M[K][2][PDSQ];   // 36864 B
    __shared__ __align__(16) float Row[EXT*ROWF];   // 21632 B
    __shared__ int   inp_sh[L];                     // 4096 B
    __shared__ float diag_sh[K][S];
    __shared__ float mue_sh[K];
    __shared__ float tau_sh;

    const int b    = blockIdx.x;
    const int t    = threadIdx.x;
    const int w    = t >> 6;          // wave id == matrix k
    const int lane = t & 63;
    const int li = lane >> 3, lj = lane & 7;
    const int r0 = 3*li, c0 = 3*lj;   // 3x3 tile origin in 24x24

    // ---- phase 0 ----
    for (int u = t; u < L; u += 512) inp_sh[u] = inputs[b*L + u];
    for (int e = t; e < EXT*ROWF; e += 512) {
        int row = e / ROWF, c = e - row*ROWF;
        int k = c / EXT, s = c - k*EXT;
        Row[e] = (row >= S && s == row) ? 1.f : 0.f;   // one-hot rows; rest 0
    }
    {
        float* Mw = &M[w][0][0];
        for (int e = lane; e < 2*PDSQ; e += 64) Mw[e] = 0.f;
    }
    if (t == 0) tau_sh = softplusf(tau_kernel[rate_indices[b]]);
    __syncthreads();

    // ---- phase 1: build A = (Q_w / mue) * tau / 2^6 in M0 ----
    float* M0 = &M[w][0][0];
    float* M1 = &M[w][1][0];
    const float* E = exch + w * SS;

    for (int e = lane; e < SS; e += 64) {
        int r = e / S, c = e - r*S;
        float v = 0.f;
        if (r != c)
            v = softplusf(0.5f * (E[r*S + c] + E[c*S + r])) * freq[c];
        M0[r*PD + c] = v;
    }
    __syncthreads();
    if (lane < S) {
        float d = 0.f;
        #pragma unroll
        for (int j = 0; j < S; ++j) d += M0[lane*PD + j];
        diag_sh[w][lane] = d;
    }
    __syncthreads();
    if (lane == 0) {
        float m = 0.f;
        #pragma unroll
        for (int s = 0; s < S; ++s) m += freq[s] * diag_sh[w][s];
        mue_sh[w] = fmaxf(m, 1e-16f);
    }
    __syncthreads();
    {
        float scale = tau_sh * 0.015625f;
        float mue   = mue_sh[w];
        for (int e = lane; e < SS; e += 64) {
            int r = e / S, c = e - r*S;
            float v = (r == c) ? -diag_sh[w][r] : M0[r*PD + c];
            M0[r*PD + c] = (v / mue) * scale;
        }
    }
    __syncthreads();

    // ---- expm: cache A cols, P=I+A, order-16 Taylor, 6 squarings ----
    float Ac[S][3];
    #pragma unroll
    for (int j = 0; j < S; ++j) {
        #pragma unroll
        for (int d = 0; d < 3; ++d)
            Ac[j][d] = M0[j*PD + c0 + d];
    }

    float P[3][3];
    #pragma unroll
    for (int dr = 0; dr < 3; ++dr)
        #pragma unroll
        for (int dc = 0; dc < 3; ++dc) {
            int r = r0 + dr, c = c0 + dc;
            P[dr][dc] = M0[r*PD + c] + ((r == c && r < S) ? 1.f : 0.f);
        }

    const float* Tc = M0;
    float* Tn = M1;
    #pragma unroll 1
    for (int i = 2; i <= 16; ++i) {
        float C[3][3] = {{0.f,0.f,0.f},{0.f,0.f,0.f},{0.f,0.f,0.f}};
        #pragma unroll
        for (int jc = 0; jc < 5; ++jc) {
            float4 a0 = *(const float4*)&Tc[(r0+0)*PD + 4*jc];
            float4 a1 = *(const float4*)&Tc[(r0+1)*PD + 4*jc];
            float4 a2 = *(const float4*)&Tc[(r0+2)*PD + 4*jc];
            float t0[4] = {a0.x, a0.y, a0.z, a0.w};
            float t1[4] = {a1.x, a1.y, a1.z, a1.w};
            float t2[4] = {a2.x, a2.y, a2.z, a2.w};
            #pragma unroll
            for (int dj = 0; dj < 4; ++dj) {
                int j = 4*jc + dj;
                #pragma unroll
                for (int dc = 0; dc < 3; ++dc) {
                    C[0][dc] = fmaf(t0[dj], Ac[j][dc], C[0][dc]);
                    C[1][dc] = fmaf(t1[dj], Ac[j][dc], C[1][dc]);
                    C[2][dc] = fmaf(t2[dj], Ac[j][dc], C[2][dc]);
                }
            }
        }
        float inv = 1.0f / (float)i;
        #pragma unroll
        for (int dr = 0; dr < 3; ++dr)
            #pragma unroll
            for (int dc = 0; dc < 3; ++dc) {
                C[dr][dc] *= inv;
                P[dr][dc] += C[dr][dc];
                Tn[(r0+dr)*PD + c0 + dc] = C[dr][dc];
            }
        __syncthreads();
        float* tmp = (float*)Tc; Tc = Tn; Tn = tmp;
    }

    #pragma unroll 1
    for (int sq = 0; sq < 6; ++sq) {
        #pragma unroll
        for (int dr = 0; dr < 3; ++dr)
            #pragma unroll
            for (int dc = 0; dc < 3; ++dc)
                Tn[(r0+dr)*PD + c0 + dc] = P[dr][dc];
        __syncthreads();
        const float* Pb = Tn;
        float C[3][3] = {{0.f,0.f,0.f},{0.f,0.f,0.f},{0.f,0.f,0.f}};
        #pragma unroll
        for (int jc = 0; jc < 5; ++jc) {
            float4 a0 = *(const float4*)&Pb[(r0+0)*PD + 4*jc];
            float4 a1 = *(const float4*)&Pb[(r0+1)*PD + 4*jc];
            float4 a2 = *(const float4*)&Pb[(r0+2)*PD + 4*jc];
            float t0[4] = {a0.x, a0.y, a0.z, a0.w};
            float t1[4] = {a1.x, a1.y, a1.z, a1.w};
            float t2[4] = {a2.x, a2.y, a2.z, a2.w};
            float cb[4][3];
            #pragma unroll
            for (int dj = 0; dj < 4; ++dj)
                #pragma unroll
                for (int dc = 0; dc < 3; ++dc)
                    cb[dj][dc] = Pb[(4*jc + dj)*PD + c0 + dc];
            #pragma unroll
            for (int dj = 0; dj < 4; ++dj)
                #pragma unroll
                for (int dc = 0; dc < 3; ++dc) {
                    C[0][dc] = fmaf(t0[dj], cb[dj][dc], C[0][dc]);
                    C[1][dc] = fmaf(t1[dj], cb[dj][dc], C[1][dc]);
                    C[2][dc] = fmaf(t2[dj], cb[dj][dc], C[2][dc]);
                }
        }
        #pragma unroll
        for (int dr = 0; dr < 3; ++dr)
            #pragma unroll
            for (int dc = 0; dc < 3; ++dc)
                P[dr][dc] = C[dr][dc];
        float* tmp = (float*)Tc; Tc = Tn; Tn = tmp;
        __syncthreads();   // writes next iter reuse buffers across waves' shared barrier schedule
    }

    // ---- P tiles -> Row LUT (rows < 20, cols k*26 + c) ----
    #pragma unroll
    for (int dr = 0; dr < 3; ++dr) {
        int r = r0 + dr; if (r >= S) continue;
        #pragma unroll
        for (int dc = 0; dc < 3; ++dc) {
            int c = c0 + dc; if (c >= S) continue;
            Row[r*ROWF + w*EXT + c] = P[dr][dc];
        }
    }
    __syncthreads();

    // ---- phase 2: stream out[b][l][:] = Row[inp[l]][:] ----
    const float4* Row4 = (const float4*)Row;
    float4* out4 = (float4*)out + (size_t)b * (BROW/4);
    for (int u = t; u < L * (ROWF/4); u += 512) {
        int l = u / (ROWF/4);          // u / 52
        int q = u - l * (ROWF/4);
        out4[u] = Row4[inp_sh[l] * (ROWF/4) + q];
    }
}

// ---------------------------------------------------------------------------
extern "C" void kernel_launch(void* const* d_in, const int* in_sizes, int n_in,
                              void* d_out, int out_size, void* d_ws, size_t ws_size,
                              hipStream_t stream) {
    const int*   inputs  = (const int*)  d_in[0];  // (B,L) int32
    const int*   rate_ix = (const int*)  d_in[1];  // (B,) int32
    const float* tau_k   = (const float*)d_in[2];  // (NR,) f32
    const float* exch    = (const float*)d_in[3];  // (K,S,S) f32
    const float* freq    = (const float*)d_in[4];  // (S,) f32
    float* out = (float*)d_out;

    (void)d_ws; (void)ws_size;  // intentionally unused

    fused_kernel<<<B, 512, 0, stream>>>(inputs, rate_ix, tau_k, exch, freq, out);
}

// Round 5
// 476.595 us; speedup vs baseline: 1.0725x; 1.0363x over previous
//
#include <hip/hip_runtime.h>
#include <math.h>

#define B    512
#define L    1024
#define K    8
#define NR   512
#define S    20
#define EXT  26
#define SS   (S*S)            // 400
#define PD   24               // padded matrix dim (zero pad is matmul-self-consistent)
#define PDSQ (PD*PD)          // 576
#define ROWF (K*EXT)          // 208 floats per (b,l)
#define BROW (L*ROWF)         // 212992 floats per b

__device__ __forceinline__ float softplusf(float x) {
    return fmaxf(x, 0.0f) + log1pf(expf(-fabsf(x)));
}

// wave-local ordering fence: per-wave DS ops complete in order on CDNA, so
// for a wave working on its OWN LDS patch this replaces __syncthreads.
__device__ __forceinline__ void wave_fence() {
    __builtin_amdgcn_wave_barrier();
}

// ---------------------------------------------------------------------------
// ONE fused kernel. Block = one b (512 blocks, 512 threads = 8 waves,
// 2 blocks/CU). Wave w owns matrix k=w in its private LDS patch M[w].
//   Phase 0: inputs[b]->LDS; Row LUT init (ONLY cells tiles never write:
//            pad cols s>=20 of P-rows, and one-hot rows) — no ordering
//            hazard with tile writes, so no barrier needed in between.
//   Phase 1: per-wave expm (8x8 lanes, 3x3 reg tile, A cols in regs),
//            order-10 Taylor (||A||^11/11! * 64 <= ~3e-4 << 2e-2 thresh)
//            + 6 squarings. ALL barriers wave-local (zero cost).
//   Phase 2: after the single __syncthreads, stream
//            out[b][l][:] = Row[inp[l]][:]; 512*13=128*52 so each thread's
//            (l,q) repeats with period 13 -> division-free, 13 independent
//            ds_read->store chains per outer iter (full latency hiding).
// ---------------------------------------------------------------------------
__global__ __launch_bounds__(512, 2) void fused_kernel(
    const int*   __restrict__ inputs,        // B,L
    const int*   __restrict__ rate_indices,  // B
    const float* __restrict__ tau_kernel,    // NR
    const float* __restrict__ exch,          // K,S,S
    const float* __restrict__ freq,          // S
    float* __restrict__ out)                 // B,L,208
{
    __shared__ __align__(16) float M[K][2][PDSQ];   // 36864 B
    __shared__ __align__(16) float Row[EXT*ROWF];   // 21632 B
    __shared__ int   inp_sh[L];                     // 4096 B
    __shared__ float diag_sh[K][S];
    __shared__ float mue_sh[K];

    const int b    = blockIdx.x;
    const int t    = threadIdx.x;
    const int w    = t >> 6;          // wave id == matrix k
    const int lane = t & 63;
    const int li = lane >> 3, lj = lane & 7;
    const int r0 = 3*li, c0 = 3*lj;   // 3x3 tile origin in 24x24

    // ---- phase 0 (no cross-wave ordering needed until the final barrier) ----
    for (int u = t; u < L; u += 512) inp_sh[u] = inputs[b*L + u];
    for (int e = t; e < EXT*ROWF; e += 512) {
        int row = e / ROWF, c = e - row*ROWF;
        int k = c / EXT, s = c - k*EXT;
        if (row < S) {
            if (s >= S) Row[e] = 0.f;              // pad cols only; P cells skipped
        } else {
            Row[e] = (s == row) ? 1.f : 0.f;       // one-hot rows
        }
    }
    float* M0 = &M[w][0][0];
    float* M1 = &M[w][1][0];
    for (int e = lane; e < 2*PDSQ; e += 64) M0[e] = 0.f;  // zero both buffers
    // tau: uniform loads, computed redundantly in every lane (removes the
    // cross-wave tau_sh dependency)
    float tau = softplusf(tau_kernel[rate_indices[b]]);
    wave_fence();

    // ---- phase 1: build A = (Q_w / mue) * tau / 2^6 in M0 ----
    const float* E = exch + w * SS;
    for (int e = lane; e < SS; e += 64) {
        int r = e / S, c = e - r*S;
        float v = 0.f;
        if (r != c)
            v = softplusf(0.5f * (E[r*S + c] + E[c*S + r])) * freq[c];
        M0[r*PD + c] = v;
    }
    wave_fence();
    if (lane < S) {
        float d = 0.f;
        #pragma unroll
        for (int j = 0; j < S; ++j) d += M0[lane*PD + j];
        diag_sh[w][lane] = d;
    }
    wave_fence();
    if (lane == 0) {
        float m = 0.f;
        #pragma unroll
        for (int s = 0; s < S; ++s) m += freq[s] * diag_sh[w][s];
        mue_sh[w] = fmaxf(m, 1e-16f);
    }
    wave_fence();
    {
        float scale = tau * 0.015625f;
        float mue   = mue_sh[w];
        for (int e = lane; e < SS; e += 64) {
            int r = e / S, c = e - r*S;
            float v = (r == c) ? -diag_sh[w][r] : M0[r*PD + c];
            M0[r*PD + c] = (v / mue) * scale;
        }
    }
    wave_fence();

    // ---- expm: A cols in regs, P=I+A, order-10 Taylor, 6 squarings ----
    float Ac[S][3];
    #pragma unroll
    for (int j = 0; j < S; ++j) {
        #pragma unroll
        for (int d = 0; d < 3; ++d)
            Ac[j][d] = M0[j*PD + c0 + d];
    }

    float P[3][3];
    #pragma unroll
    for (int dr = 0; dr < 3; ++dr)
        #pragma unroll
        for (int dc = 0; dc < 3; ++dc) {
            int r = r0 + dr, c = c0 + dc;
            P[dr][dc] = M0[r*PD + c] + ((r == c && r < S) ? 1.f : 0.f);
        }

    const float* Tc = M0;
    float* Tn = M1;
    #pragma unroll 1
    for (int i = 2; i <= 10; ++i) {
        float C[3][3] = {{0.f,0.f,0.f},{0.f,0.f,0.f},{0.f,0.f,0.f}};
        #pragma unroll
        for (int jc = 0; jc < 5; ++jc) {
            float4 a0 = *(const float4*)&Tc[(r0+0)*PD + 4*jc];
            float4 a1 = *(const float4*)&Tc[(r0+1)*PD + 4*jc];
            float4 a2 = *(const float4*)&Tc[(r0+2)*PD + 4*jc];
            float t0[4] = {a0.x, a0.y, a0.z, a0.w};
            float t1[4] = {a1.x, a1.y, a1.z, a1.w};
            float t2[4] = {a2.x, a2.y, a2.z, a2.w};
            #pragma unroll
            for (int dj = 0; dj < 4; ++dj) {
                int j = 4*jc + dj;
                #pragma unroll
                for (int dc = 0; dc < 3; ++dc) {
                    C[0][dc] = fmaf(t0[dj], Ac[j][dc], C[0][dc]);
                    C[1][dc] = fmaf(t1[dj], Ac[j][dc], C[1][dc]);
                    C[2][dc] = fmaf(t2[dj], Ac[j][dc], C[2][dc]);
                }
            }
        }
        float inv = 1.0f / (float)i;
        #pragma unroll
        for (int dr = 0; dr < 3; ++dr)
            #pragma unroll
            for (int dc = 0; dc < 3; ++dc) {
                C[dr][dc] *= inv;
                P[dr][dc] += C[dr][dc];
                Tn[(r0+dr)*PD + c0 + dc] = C[dr][dc];
            }
        wave_fence();
        float* tmp = (float*)Tc; Tc = Tn; Tn = tmp;
    }

    #pragma unroll 1
    for (int sq = 0; sq < 6; ++sq) {
        #pragma unroll
        for (int dr = 0; dr < 3; ++dr)
            #pragma unroll
            for (int dc = 0; dc < 3; ++dc)
                Tn[(r0+dr)*PD + c0 + dc] = P[dr][dc];
        wave_fence();
        const float* Pb = Tn;
        float C[3][3] = {{0.f,0.f,0.f},{0.f,0.f,0.f},{0.f,0.f,0.f}};
        #pragma unroll
        for (int jc = 0; jc < 5; ++jc) {
            float4 a0 = *(const float4*)&Pb[(r0+0)*PD + 4*jc];
            float4 a1 = *(const float4*)&Pb[(r0+1)*PD + 4*jc];
            float4 a2 = *(const float4*)&Pb[(r0+2)*PD + 4*jc];
            float t0[4] = {a0.x, a0.y, a0.z, a0.w};
            float t1[4] = {a1.x, a1.y, a1.z, a1.w};
            float t2[4] = {a2.x, a2.y, a2.z, a2.w};
            float cb[4][3];
            #pragma unroll
            for (int dj = 0; dj < 4; ++dj)
                #pragma unroll
                for (int dc = 0; dc < 3; ++dc)
                    cb[dj][dc] = Pb[(4*jc + dj)*PD + c0 + dc];
            #pragma unroll
            for (int dj = 0; dj < 4; ++dj)
                #pragma unroll
                for (int dc = 0; dc < 3; ++dc) {
                    C[0][dc] = fmaf(t0[dj], cb[dj][dc], C[0][dc]);
                    C[1][dc] = fmaf(t1[dj], cb[dj][dc], C[1][dc]);
                    C[2][dc] = fmaf(t2[dj], cb[dj][dc], C[2][dc]);
                }
        }
        #pragma unroll
        for (int dr = 0; dr < 3; ++dr)
            #pragma unroll
            for (int dc = 0; dc < 3; ++dc)
                P[dr][dc] = C[dr][dc];
        float* tmp = (float*)Tc; Tc = Tn; Tn = tmp;
        wave_fence();
    }

    // ---- P tiles -> Row LUT (only r<20, c<20 cells; disjoint from init) ----
    #pragma unroll
    for (int dr = 0; dr < 3; ++dr) {
        int r = r0 + dr; if (r >= S) continue;
        #pragma unroll
        for (int dc = 0; dc < 3; ++dc) {
            int c = c0 + dc; if (c >= S) continue;
            Row[r*ROWF + w*EXT + c] = P[dr][dc];
        }
    }
    __syncthreads();   // the ONLY block-wide barrier

    // ---- phase 2: division-free streaming store ----
    // u = t + 512*j + 6656*i  (j<13, i<8); 6656 = 128*52 so q is j-periodic.
    int l0[13], qq[13];
    {
        int uu = t;
        #pragma unroll
        for (int j = 0; j < 13; ++j) {
            l0[j] = uu / 52;
            qq[j] = uu - l0[j] * 52;
            uu += 512;
        }
    }
    const float4* Row4 = (const float4*)Row;
    float4* out4 = (float4*)out + (size_t)b * (BROW/4);
    #pragma unroll 1
    for (int i = 0; i < 8; ++i) {
        int lbase = i << 7;          // 128*i
        int ubase = t + i * 6656;
        #pragma unroll
        for (int j = 0; j < 13; ++j) {
            int inp = inp_sh[l0[j] + lbase];
            out4[ubase + (j << 9)] = Row4[inp * 52 + qq[j]];
        }
    }
}

// ---------------------------------------------------------------------------
extern "C" void kernel_launch(void* const* d_in, const int* in_sizes, int n_in,
                              void* d_out, int out_size, void* d_ws, size_t ws_size,
                              hipStream_t stream) {
    const int*   inputs  = (const int*)  d_in[0];  // (B,L) int32
    const int*   rate_ix = (const int*)  d_in[1];  // (B,) int32
    const float* tau_k   = (const float*)d_in[2];  // (NR,) f32
    const float* exch    = (const float*)d_in[3];  // (K,S,S) f32
    const float* freq    = (const float*)d_in[4];  // (S,) f32
    float* out = (float*)d_out;

    (void)d_ws; (void)ws_size;  // intentionally unused

    fused_kernel<<<B, 512, 0, stream>>>(inputs, rate_ix, tau_k, exch, freq, out);
}